// Round 3
// baseline (2637.233 us; speedup 1.0000x reference)
//
#include <hip/hip_runtime.h>
#include <hip/hip_fp16.h>

#define T_LEN 4096
#define BATCH 256
#define HID   25
#define G4    100
#define CH    16
#define NCHUNK (T_LEN / CH)

typedef float v2f __attribute__((ext_vector_type(2)));

#define DEV __device__ __forceinline__

DEV float rcpf_(float x){
#if __has_builtin(__builtin_amdgcn_rcpf)
    return __builtin_amdgcn_rcpf(x);
#else
    return 1.0f / x;
#endif
}
DEV float readlane_f(float v, int j){
#if __has_builtin(__builtin_amdgcn_readlane)
    return __int_as_float(__builtin_amdgcn_readlane(__float_as_int(v), j));
#else
    return __shfl(v, j);
#endif
}
DEV v2f fma2(v2f a, v2f b, v2f c){
#if __has_builtin(__builtin_elementwise_fma)
    return __builtin_elementwise_fma(a, b, c);
#else
    v2f r; r.x = fmaf(a.x, b.x, c.x); r.y = fmaf(a.y, b.y, c.y); return r;
#endif
}
DEV float dot2acc(unsigned w, unsigned xv, float acc){
#if __has_builtin(__builtin_amdgcn_fdot2)
    typedef _Float16 h2v __attribute__((ext_vector_type(2)));
    return __builtin_amdgcn_fdot2(__builtin_bit_cast(h2v, w),
                                  __builtin_bit_cast(h2v, xv), acc, false);
#else
    __half2 a = __builtin_bit_cast(__half2, w), b2 = __builtin_bit_cast(__half2, xv);
    float2 fa = __half22float2(a), fb = __half22float2(b2);
    return acc + fa.x * fb.x + fa.y * fb.y;
#endif
}
DEV float sigm_(float x){ return 1.0f - rcpf_(__expf(x) + 1.0f); }
DEV float tanhx_(float x){ return 1.0f - 2.0f * rcpf_(__expf(2.0f * x) + 1.0f); }

DEV void fence_lgkm(){ asm volatile("s_waitcnt lgkmcnt(0)" ::: "memory"); }
// raw barrier: no vmcnt drain (keeps producer's global loads in flight)
DEV void sync2(){ fence_lgkm(); __builtin_amdgcn_s_barrier(); asm volatile("" ::: "memory"); }

// ---------------- consumer: 4 gates per lane, lane-local cell update ----------------
// xg layout per timestep: [unit k][4] = {i,f,g,o} projections  -> one ds_read_b128/step
template<bool STORE>
DEV void lstm_consumer(const float* __restrict__ w_hh,
                       const float* __restrict__ b_ih, const float* __restrict__ b_hh,
                       const float (*xg)[CH][G4], int lane,
                       __half* __restrict__ sptr, long long sstride,
                       float* __restrict__ h_final)
{
    const int k = (lane < HID) ? lane : 0;   // lanes >=25 duplicate unit 0 (harmless)

    v2f wif[HID], wgo[HID];
    #pragma unroll
    for (int j = 0; j < HID; ++j) {
        wif[j].x = w_hh[(0 * HID + k) * HID + j];
        wif[j].y = w_hh[(1 * HID + k) * HID + j];
        wgo[j].x = w_hh[(2 * HID + k) * HID + j];
        wgo[j].y = w_hh[(3 * HID + k) * HID + j];
    }
    v2f bif, bgo;
    bif.x = b_ih[k] + b_hh[k];
    bif.y = b_ih[HID + k] + b_hh[HID + k];
    bgo.x = b_ih[2 * HID + k] + b_hh[2 * HID + k];
    bgo.y = b_ih[3 * HID + k] + b_hh[3 * HID + k];

    float h = 0.0f, cst = 0.0f;

    sync2();                                   // chunk 0 ready
    for (int c = 0; c < NCHUNK; ++c) {
        const float* buf = &xg[c & 1][0][0];
        #pragma unroll 4
        for (int t = 0; t < CH; ++t) {
            float4 x4 = ((const float4*)(buf + t * G4))[k];
            v2f aif0, ago0, aif1, ago1;
            aif0.x = bif.x + x4.x; aif0.y = bif.y + x4.y;
            ago0.x = bgo.x + x4.z; ago0.y = bgo.y + x4.w;
            aif1.x = 0.f; aif1.y = 0.f; ago1.x = 0.f; ago1.y = 0.f;
            #pragma unroll
            for (int j = 0; j < HID; j += 2) {
                float hs0 = readlane_f(h, j);
                v2f h20; h20.x = hs0; h20.y = hs0;
                aif0 = fma2(wif[j], h20, aif0);
                ago0 = fma2(wgo[j], h20, ago0);
                if (j + 1 < HID) {
                    float hs1 = readlane_f(h, j + 1);
                    v2f h21; h21.x = hs1; h21.y = hs1;
                    aif1 = fma2(wif[j + 1], h21, aif1);
                    ago1 = fma2(wgo[j + 1], h21, ago1);
                }
            }
            v2f aif = aif0 + aif1, ago = ago0 + ago1;
            float si = sigm_(aif.x);
            float sf = sigm_(aif.y);
            float tg = tanhx_(ago.x);
            float so = sigm_(ago.y);
            cst = sf * cst + si * tg;          // lane-local, no cross-lane
            h   = so * tanhx_(cst);
            if (STORE) {
                if (lane < HID) *sptr = __float2half(h);
                sptr += sstride;
            }
        }
        sync2();
    }
    if (!STORE && lane < HID) h_final[lane] = h;
}

// ================= Layer 0: one block per (batch, dir); wave0=recurrence, wave1=xg producer =================
__global__ __launch_bounds__(128, 1) void lstm_l0(
    const float* __restrict__ x,
    const float* __restrict__ w_ih_f, const float* __restrict__ w_hh_f,
    const float* __restrict__ b_ih_f, const float* __restrict__ b_hh_f,
    const float* __restrict__ w_ih_b, const float* __restrict__ w_hh_b,
    const float* __restrict__ b_ih_b, const float* __restrict__ b_hh_b,
    __half* __restrict__ h0)                       // [B,T,50]
{
    const int b    = blockIdx.x;
    const int dir  = blockIdx.y;
    const int tid  = threadIdx.x;
    const int lane = tid & 63;
    const int wave = tid >> 6;

    const float* w_ih = dir ? w_ih_b : w_ih_f;
    const float* w_hh = dir ? w_hh_b : w_hh_f;
    const float* b_ih = dir ? b_ih_b : b_ih_f;
    const float* b_hh = dir ? b_hh_b : b_hh_f;

    __shared__ __align__(16) float xg[2][CH][G4];  // transposed: [t][unit][4]
    __shared__ __align__(16) float xs[CH][28];

    if (wave == 1) {
        // producer: xg[t][k][q] = w_ih[row q*25+k, :] . x[t,:]
        const int g0 = (lane < 50) ? lane : 0;
        const int q0 = g0 / HID, k0 = g0 % HID;
        float w0[HID], w1[HID];
        #pragma unroll
        for (int k = 0; k < HID; ++k) { w0[k] = w_ih[g0 * HID + k]; w1[k] = w_ih[(g0 + 50) * HID + k]; }

        for (int cc = 0; cc <= NCHUNK; ++cc) {
            if (cc < NCHUNK) {
                const int row0 = dir ? (T_LEN - CH - cc * CH) : (cc * CH);
                const float* src = x + ((size_t)b * T_LEN + row0) * HID;
                #pragma unroll
                for (int i = 0; i < 7; ++i) {
                    int idx = lane + 64 * i;
                    if (idx < CH * HID) {
                        float v = src[idx];
                        int r = idx / HID, col = idx - r * HID;
                        xs[dir ? (CH - 1 - r) : r][col] = v;
                    }
                }
                fence_lgkm();
                float (*dst)[G4] = xg[cc & 1];
                for (int t = 0; t < CH; ++t) {
                    const float* xr = xs[t];
                    float accA[4] = {0,0,0,0}, accB[4] = {0,0,0,0};
                    #pragma unroll
                    for (int k = 0; k < HID; ++k) {
                        float xv = xr[k];
                        accA[k & 3] += w0[k] * xv;
                        accB[k & 3] += w1[k] * xv;
                    }
                    if (lane < 50) {
                        dst[t][k0 * 4 + q0]     = (accA[0] + accA[1]) + (accA[2] + accA[3]);
                        dst[t][k0 * 4 + q0 + 2] = (accB[0] + accB[1]) + (accB[2] + accB[3]);
                    }
                }
            }
            sync2();
        }
    } else {
        __half* sptr = h0 + ((size_t)b * T_LEN + (dir ? (T_LEN - 1) : 0)) * (2 * HID)
                          + (size_t)(dir * HID) + lane;
        const long long sstride = dir ? -(long long)(2 * HID) : (long long)(2 * HID);
        lstm_consumer<true>(w_hh, b_ih, b_hh, xg, lane, sptr, sstride, nullptr);
    }
}

// ================= Layer 1 forward: one block per batch; only final h kept =================
__global__ __launch_bounds__(128, 1) void lstm_l1f(
    const __half* __restrict__ h0,                 // [B,T,50]
    const float* __restrict__ w_ih, const float* __restrict__ w_hh,
    const float* __restrict__ b_ih, const float* __restrict__ b_hh,
    float* __restrict__ hf)                        // [B,25]
{
    const int b    = blockIdx.x;
    const int tid  = threadIdx.x;
    const int lane = tid & 63;
    const int wave = tid >> 6;

    __shared__ __align__(16) float xg[2][CH][G4];
    __shared__ __align__(16) unsigned xs[CH][28];  // rows of 25 dwords = 50 halves

    if (wave == 1) {
        const int g0 = (lane < 50) ? lane : 0;
        const int q0 = g0 / HID, k0 = g0 % HID;
        unsigned wp0[HID], wp1[HID];
        #pragma unroll
        for (int k = 0; k < HID; ++k) {
            __half2 a  = __floats2half2_rn(w_ih[g0 * (2 * HID) + 2 * k], w_ih[g0 * (2 * HID) + 2 * k + 1]);
            __half2 c2 = __floats2half2_rn(w_ih[(g0 + 50) * (2 * HID) + 2 * k], w_ih[(g0 + 50) * (2 * HID) + 2 * k + 1]);
            wp0[k] = __builtin_bit_cast(unsigned, a);
            wp1[k] = __builtin_bit_cast(unsigned, c2);
        }
        const unsigned* hsrc = (const unsigned*)h0;
        for (int cc = 0; cc <= NCHUNK; ++cc) {
            if (cc < NCHUNK) {
                const unsigned* src = hsrc + ((size_t)b * T_LEN + cc * CH) * HID;
                #pragma unroll
                for (int i = 0; i < 7; ++i) {
                    int idx = lane + 64 * i;
                    if (idx < CH * HID) {
                        unsigned v = src[idx];
                        int r = idx / HID, col = idx - r * HID;
                        xs[r][col] = v;
                    }
                }
                fence_lgkm();
                float (*dst)[G4] = xg[cc & 1];
                for (int t = 0; t < CH; ++t) {
                    const unsigned* xr = xs[t];
                    float accA[4] = {0,0,0,0}, accB[4] = {0,0,0,0};
                    #pragma unroll
                    for (int k = 0; k < HID; ++k) {
                        unsigned xv = xr[k];
                        accA[k & 3] = dot2acc(wp0[k], xv, accA[k & 3]);
                        accB[k & 3] = dot2acc(wp1[k], xv, accB[k & 3]);
                    }
                    if (lane < 50) {
                        dst[t][k0 * 4 + q0]     = (accA[0] + accA[1]) + (accA[2] + accA[3]);
                        dst[t][k0 * 4 + q0 + 2] = (accB[0] + accB[1]) + (accB[2] + accB[3]);
                    }
                }
            }
            sync2();
        }
    } else {
        lstm_consumer<false>(w_hh, b_ih, b_hh, xg, lane, nullptr, 0, hf + (size_t)b * HID);
    }
}

// ================= Layer 1 backward (1 step from zero state) + FC head =================
__global__ __launch_bounds__(128) void final_kernel(
    const __half* __restrict__ h0,
    const float* __restrict__ hf,
    const float* __restrict__ w_ih1b,
    const float* __restrict__ b_ih1b, const float* __restrict__ b_hh1b,
    const float* __restrict__ fc2_w, const float* __restrict__ fc2_b,
    float* __restrict__ out)
{
    const int b   = blockIdx.x;
    const int tid = threadIdx.x;

    __shared__ float inb[2 * HID];
    __shared__ float act[G4];
    __shared__ float hb[HID];

    if (tid < HID) {
        const __half2* rr = (const __half2*)(h0 + ((size_t)b * T_LEN + (T_LEN - 1)) * (2 * HID));
        float2 v = __half22float2(rr[tid]);
        inb[2 * tid] = v.x; inb[2 * tid + 1] = v.y;
    }
    __syncthreads();

    if (tid < G4) {
        float g = b_ih1b[tid] + b_hh1b[tid];
        #pragma unroll
        for (int k = 0; k < 2 * HID; ++k) g += w_ih1b[tid * (2 * HID) + k] * inb[k];
        act[tid] = (tid >= 2 * HID && tid < 3 * HID) ? tanhx_(g) : sigm_(g);
    }
    __syncthreads();

    if (tid < HID) {
        float c = act[tid] * act[2 * HID + tid];   // c0 = 0
        hb[tid] = act[3 * HID + tid] * tanhx_(c);
    }
    __syncthreads();

    if (tid == 0) {
        float s = fc2_b[0];
        #pragma unroll
        for (int k = 0; k < HID; ++k) s += fmaxf(hf[b * HID + k], 0.0f) * fc2_w[k];
        #pragma unroll
        for (int k = 0; k < HID; ++k) s += fmaxf(hb[k], 0.0f) * fc2_w[HID + k];
        s = fmaxf(s, 0.0f);
        out[b] = 1.0f / (1.0f + __expf(-s));
    }
}

extern "C" void kernel_launch(void* const* d_in, const int* in_sizes, int n_in,
                              void* d_out, int out_size, void* d_ws, size_t ws_size,
                              hipStream_t stream)
{
    const float* x        = (const float*)d_in[0];
    const float* w_ih_l0f = (const float*)d_in[1];
    const float* w_hh_l0f = (const float*)d_in[2];
    const float* b_ih_l0f = (const float*)d_in[3];
    const float* b_hh_l0f = (const float*)d_in[4];
    const float* w_ih_l0b = (const float*)d_in[5];
    const float* w_hh_l0b = (const float*)d_in[6];
    const float* b_ih_l0b = (const float*)d_in[7];
    const float* b_hh_l0b = (const float*)d_in[8];
    const float* w_ih_l1f = (const float*)d_in[9];
    const float* w_hh_l1f = (const float*)d_in[10];
    const float* b_ih_l1f = (const float*)d_in[11];
    const float* b_hh_l1f = (const float*)d_in[12];
    const float* w_ih_l1b = (const float*)d_in[13];
    const float* b_ih_l1b = (const float*)d_in[15];
    const float* b_hh_l1b = (const float*)d_in[16];
    const float* fc2_w    = (const float*)d_in[17];
    const float* fc2_b    = (const float*)d_in[18];
    float* out = (float*)d_out;

    __half* h0 = (__half*)d_ws;   // [B,T,50] fp16
    float*  hf = (float*)((char*)d_ws + (size_t)BATCH * T_LEN * 2 * HID * sizeof(__half));

    dim3 g0(BATCH, 2);
    lstm_l0<<<g0, 128, 0, stream>>>(x,
        w_ih_l0f, w_hh_l0f, b_ih_l0f, b_hh_l0f,
        w_ih_l0b, w_hh_l0b, b_ih_l0b, b_hh_l0b, h0);

    lstm_l1f<<<BATCH, 128, 0, stream>>>(h0,
        w_ih_l1f, w_hh_l1f, b_ih_l1f, b_hh_l1f, hf);

    final_kernel<<<BATCH, 128, 0, stream>>>(h0, hf,
        w_ih_l1b, b_ih_l1b, b_hh_l1b, fc2_w, fc2_b, out);
}

// Round 4
// 2499.044 us; speedup vs baseline: 1.0553x; 1.0553x over previous
//
#include <hip/hip_runtime.h>
#include <hip/hip_fp16.h>

#define T_LEN 4096
#define BATCH 256
#define HID   25
#define G4    100
#define CH    16
#define NCHUNK (T_LEN / CH)

#define LOG2E  1.4426950408889634f
#define LOG2E2 2.8853900817779268f

typedef float v2f __attribute__((ext_vector_type(2)));

#define DEV __device__ __forceinline__

DEV float rcpf_(float x){
#if __has_builtin(__builtin_amdgcn_rcpf)
    return __builtin_amdgcn_rcpf(x);
#else
    return 1.0f / x;
#endif
}
DEV float readlane_f(float v, int j){
#if __has_builtin(__builtin_amdgcn_readlane)
    return __int_as_float(__builtin_amdgcn_readlane(__float_as_int(v), j));
#else
    return __shfl(v, j);
#endif
}
DEV v2f fma2(v2f a, v2f b, v2f c){
#if __has_builtin(__builtin_elementwise_fma)
    return __builtin_elementwise_fma(a, b, c);
#else
    v2f r; r.x = fmaf(a.x, b.x, c.x); r.y = fmaf(a.y, b.y, c.y); return r;
#endif
}
DEV float dot2acc(unsigned w, unsigned xv, float acc){
#if __has_builtin(__builtin_amdgcn_fdot2)
    typedef _Float16 h2v __attribute__((ext_vector_type(2)));
    return __builtin_amdgcn_fdot2(__builtin_bit_cast(h2v, w),
                                  __builtin_bit_cast(h2v, xv), acc, false);
#else
    __half2 a = __builtin_bit_cast(__half2, w), b2 = __builtin_bit_cast(__half2, xv);
    float2 fa = __half22float2(a), fb = __half22float2(b2);
    return acc + fa.x * fb.x + fa.y * fb.y;
#endif
}
DEV float sigm_(float x){ return 1.0f - rcpf_(__expf(x) + 1.0f); }
DEV float tanhx_(float x){ return 1.0f - 2.0f * rcpf_(__expf(2.0f * x) + 1.0f); }

// row0-broadcast: every lane receives the value held by lane (lane&31) of the lower half.
// v_permlane32_swap_b32 with both inputs = v: output[PLS_ROW0] = {row0, row0}.
#define PLS_ROW0 0
DEV float bcast_row0(float v){
#if __has_builtin(__builtin_amdgcn_permlane32_swap)
    auto r = __builtin_amdgcn_permlane32_swap(__float_as_int(v), __float_as_int(v), false, false);
    return __int_as_float(r[PLS_ROW0]);
#else
    return __shfl(v, (int)(threadIdx.x & 31), 64);
#endif
}

DEV void fence_lgkm(){ asm volatile("s_waitcnt lgkmcnt(0)" ::: "memory"); }
// raw barrier: no vmcnt drain (keeps producer's global loads in flight)
DEV void sync2(){ fence_lgkm(); __builtin_amdgcn_s_barrier(); asm volatile("" ::: "memory"); }

// ---------------- consumer: lane k = gates (i,f), lane 32+k = gates (g,o); cell on upper half ----------------
// xg layout per timestep: [unit k][4] = {i,f,g,o}, bias pre-added, log2e pre-scaled (2*log2e for g)
template<bool STORE>
DEV void lstm_consumer(const float* __restrict__ w_hh,
                       const float (*xg)[CH][G4], int lane,
                       __half* sptr, long long sstride,
                       float* __restrict__ h_final)
{
    const int k   = ((lane & 31) < HID) ? (lane & 31) : 0;
    const bool up = lane >= 32;
    const int rowA = up ? (2 * HID + k) : k;          // g : i
    const int rowB = up ? (3 * HID + k) : (HID + k);  // o : f
    const float scA = up ? LOG2E2 : LOG2E;

    v2f wv[HID];
    #pragma unroll
    for (int j = 0; j < HID; ++j) {
        v2f w;
        w.x = w_hh[rowA * HID + j] * scA;
        w.y = w_hh[rowB * HID + j] * LOG2E;
        asm volatile("" : "+v"(w));        // pin: forbid remat/reload inside the loop
        wv[j] = w;
    }
    const float coef = up ? 2.0f : 1.0f;
    const bool store_lane = up && ((lane & 31) < HID);
    float h = 0.0f, cst = 0.0f;
    const int xbyte = k * 16 + (up ? 8 : 0);

    sync2();                                // chunk 0 ready
    for (int c = 0; c < NCHUNK; ++c) {
        const char* buf = (const char*)&xg[c & 1][0][0] + xbyte;
        #pragma unroll 4
        for (int t = 0; t < CH; ++t) {
            v2f a0 = *(const v2f*)(buf + t * (G4 * 4));   // {xg_A, xg_B} incl. bias
            v2f a1 = {0.f, 0.f}, a2 = {0.f, 0.f}, a3 = {0.f, 0.f};
            #pragma unroll
            for (int j = 0; j < HID; ++j) {
                float hs = readlane_f(h, 32 + j);
                v2f hv; hv.x = hs; hv.y = hs;
                if      ((j & 3) == 0) a0 = fma2(wv[j], hv, a0);
                else if ((j & 3) == 1) a1 = fma2(wv[j], hv, a1);
                else if ((j & 3) == 2) a2 = fma2(wv[j], hv, a2);
                else                   a3 = fma2(wv[j], hv, a3);
            }
            v2f a = (a0 + a1) + (a2 + a3);
            float e0 = __builtin_exp2f(a.x);
            float e1 = __builtin_exp2f(a.y);
            float u0 = 1.0f - coef * rcpf_(e0 + 1.0f);  // lower: sig(i); upper: tanh(g)
            float u1 = 1.0f - rcpf_(e1 + 1.0f);         // lower: sig(f); upper: sig(o)
            float si = bcast_row0(u0);                  // sig(i_k) on all lanes
            float sf = bcast_row0(u1);                  // sig(f_k) on all lanes
            cst = sf * cst + si * u0;                   // upper: f*c + i*tanh(g)  (lower: bounded garbage)
            float tc = 1.0f - 2.0f * rcpf_(__builtin_exp2f(LOG2E2 * cst) + 1.0f);
            h = u1 * tc;                                // upper: sig(o)*tanh(c)
            if (STORE) {
                if (store_lane) *sptr = __float2half(h);
                sptr += sstride;
            }
        }
        sync2();
    }
    if (!STORE && store_lane) h_final[k] = h;
}

// ================= Layer 0: one block per (batch, dir); wave0=recurrence, wave1=xg producer =================
__global__ __launch_bounds__(128, 1) void lstm_l0(
    const float* __restrict__ x,
    const float* __restrict__ w_ih_f, const float* __restrict__ w_hh_f,
    const float* __restrict__ b_ih_f, const float* __restrict__ b_hh_f,
    const float* __restrict__ w_ih_b, const float* __restrict__ w_hh_b,
    const float* __restrict__ b_ih_b, const float* __restrict__ b_hh_b,
    __half* __restrict__ h0)                       // [B,T,50]
{
    const int b    = blockIdx.x;
    const int dir  = blockIdx.y;
    const int tid  = threadIdx.x;
    const int lane = tid & 63;
    const int wave = tid >> 6;

    const float* w_ih = dir ? w_ih_b : w_ih_f;
    const float* w_hh = dir ? w_hh_b : w_hh_f;
    const float* b_ih = dir ? b_ih_b : b_ih_f;
    const float* b_hh = dir ? b_hh_b : b_hh_f;

    __shared__ __align__(16) float xg[2][CH][G4];  // [t][unit][{i,f,g,o}], scaled, bias included
    __shared__ __align__(16) float xs[CH][28];

    if (wave == 1) {
        const int g0 = (lane < 50) ? lane : 0;
        const int q0 = g0 / HID, r0 = g0 % HID;
        const int g1 = g0 + 50;
        const float sc0 = LOG2E;
        const float sc1 = (g0 < HID) ? LOG2E2 : LOG2E;   // rows 50..74 = g-gate
        float w0[HID], w1[HID];
        #pragma unroll
        for (int kk = 0; kk < HID; ++kk) {
            float a = w_ih[g0 * HID + kk] * sc0;
            float c = w_ih[g1 * HID + kk] * sc1;
            asm volatile("" : "+v"(a), "+v"(c));
            w0[kk] = a; w1[kk] = c;
        }
        const float bias0 = (b_ih[g0] + b_hh[g0]) * sc0;
        const float bias1 = (b_ih[g1] + b_hh[g1]) * sc1;

        for (int cc = 0; cc <= NCHUNK; ++cc) {
            if (cc < NCHUNK) {
                const int row0 = dir ? (T_LEN - CH - cc * CH) : (cc * CH);
                const float* src = x + ((size_t)b * T_LEN + row0) * HID;
                #pragma unroll
                for (int i = 0; i < 7; ++i) {
                    int idx = lane + 64 * i;
                    if (idx < CH * HID) {
                        float v = src[idx];
                        int r = idx / HID, col = idx - r * HID;
                        xs[dir ? (CH - 1 - r) : r][col] = v;
                    }
                }
                fence_lgkm();
                float (*dst)[G4] = xg[cc & 1];
                for (int t = 0; t < CH; ++t) {
                    const float* xr = xs[t];
                    float accA[4] = {bias0, 0, 0, 0}, accB[4] = {bias1, 0, 0, 0};
                    #pragma unroll
                    for (int kk = 0; kk < HID; ++kk) {
                        float xv = xr[kk];
                        accA[kk & 3] += w0[kk] * xv;
                        accB[kk & 3] += w1[kk] * xv;
                    }
                    if (lane < 50) {
                        dst[t][r0 * 4 + q0]     = (accA[0] + accA[1]) + (accA[2] + accA[3]);
                        dst[t][r0 * 4 + q0 + 2] = (accB[0] + accB[1]) + (accB[2] + accB[3]);
                    }
                }
            }
            sync2();
        }
    } else {
        const int k = ((lane & 31) < HID) ? (lane & 31) : 0;
        __half* sptr = h0 + ((size_t)b * T_LEN + (dir ? (T_LEN - 1) : 0)) * (2 * HID)
                          + (size_t)(dir * HID) + k;
        const long long sstride = dir ? -(long long)(2 * HID) : (long long)(2 * HID);
        lstm_consumer<true>(w_hh, xg, lane, sptr, sstride, nullptr);
    }
}

// ================= Layer 1 forward: one block per batch; only final h kept =================
__global__ __launch_bounds__(128, 1) void lstm_l1f(
    const __half* __restrict__ h0,                 // [B,T,50]
    const float* __restrict__ w_ih, const float* __restrict__ w_hh,
    const float* __restrict__ b_ih, const float* __restrict__ b_hh,
    float* __restrict__ hf)                        // [B,25]
{
    const int b    = blockIdx.x;
    const int tid  = threadIdx.x;
    const int lane = tid & 63;
    const int wave = tid >> 6;

    __shared__ __align__(16) float xg[2][CH][G4];
    __shared__ __align__(16) unsigned xs[CH][28];  // rows of 25 dwords = 50 halves

    if (wave == 1) {
        const int g0 = (lane < 50) ? lane : 0;
        const int q0 = g0 / HID, r0 = g0 % HID;
        const int g1 = g0 + 50;
        const float sc0 = LOG2E;
        const float sc1 = (g0 < HID) ? LOG2E2 : LOG2E;
        unsigned wp0[HID], wp1[HID];
        #pragma unroll
        for (int kk = 0; kk < HID; ++kk) {
            __half2 a  = __floats2half2_rn(w_ih[g0 * (2 * HID) + 2 * kk] * sc0,
                                           w_ih[g0 * (2 * HID) + 2 * kk + 1] * sc0);
            __half2 c2 = __floats2half2_rn(w_ih[g1 * (2 * HID) + 2 * kk] * sc1,
                                           w_ih[g1 * (2 * HID) + 2 * kk + 1] * sc1);
            unsigned ua = __builtin_bit_cast(unsigned, a);
            unsigned uc = __builtin_bit_cast(unsigned, c2);
            asm volatile("" : "+v"(ua), "+v"(uc));
            wp0[kk] = ua; wp1[kk] = uc;
        }
        const float bias0 = (b_ih[g0] + b_hh[g0]) * sc0;
        const float bias1 = (b_ih[g1] + b_hh[g1]) * sc1;
        const unsigned* hsrc = (const unsigned*)h0;
        for (int cc = 0; cc <= NCHUNK; ++cc) {
            if (cc < NCHUNK) {
                const unsigned* src = hsrc + ((size_t)b * T_LEN + cc * CH) * HID;
                #pragma unroll
                for (int i = 0; i < 7; ++i) {
                    int idx = lane + 64 * i;
                    if (idx < CH * HID) {
                        unsigned v = src[idx];
                        int r = idx / HID, col = idx - r * HID;
                        xs[r][col] = v;
                    }
                }
                fence_lgkm();
                float (*dst)[G4] = xg[cc & 1];
                for (int t = 0; t < CH; ++t) {
                    const unsigned* xr = xs[t];
                    float accA[4] = {bias0, 0, 0, 0}, accB[4] = {bias1, 0, 0, 0};
                    #pragma unroll
                    for (int kk = 0; kk < HID; ++kk) {
                        unsigned xv = xr[kk];
                        accA[kk & 3] = dot2acc(wp0[kk], xv, accA[kk & 3]);
                        accB[kk & 3] = dot2acc(wp1[kk], xv, accB[kk & 3]);
                    }
                    if (lane < 50) {
                        dst[t][r0 * 4 + q0]     = (accA[0] + accA[1]) + (accA[2] + accA[3]);
                        dst[t][r0 * 4 + q0 + 2] = (accB[0] + accB[1]) + (accB[2] + accB[3]);
                    }
                }
            }
            sync2();
        }
    } else {
        lstm_consumer<false>(w_hh, xg, lane, nullptr, 0, hf + (size_t)b * HID);
    }
}

// ================= Layer 1 backward (1 step from zero state) + FC head =================
__global__ __launch_bounds__(128) void final_kernel(
    const __half* __restrict__ h0,
    const float* __restrict__ hf,
    const float* __restrict__ w_ih1b,
    const float* __restrict__ b_ih1b, const float* __restrict__ b_hh1b,
    const float* __restrict__ fc2_w, const float* __restrict__ fc2_b,
    float* __restrict__ out)
{
    const int b   = blockIdx.x;
    const int tid = threadIdx.x;

    __shared__ float inb[2 * HID];
    __shared__ float act[G4];
    __shared__ float hb[HID];

    if (tid < HID) {
        const __half2* rr = (const __half2*)(h0 + ((size_t)b * T_LEN + (T_LEN - 1)) * (2 * HID));
        float2 v = __half22float2(rr[tid]);
        inb[2 * tid] = v.x; inb[2 * tid + 1] = v.y;
    }
    __syncthreads();

    if (tid < G4) {
        float g = b_ih1b[tid] + b_hh1b[tid];
        #pragma unroll
        for (int kk = 0; kk < 2 * HID; ++kk) g += w_ih1b[tid * (2 * HID) + kk] * inb[kk];
        act[tid] = (tid >= 2 * HID && tid < 3 * HID) ? tanhx_(g) : sigm_(g);
    }
    __syncthreads();

    if (tid < HID) {
        float c = act[tid] * act[2 * HID + tid];   // c0 = 0
        hb[tid] = act[3 * HID + tid] * tanhx_(c);
    }
    __syncthreads();

    if (tid == 0) {
        float s = fc2_b[0];
        #pragma unroll
        for (int kk = 0; kk < HID; ++kk) s += fmaxf(hf[b * HID + kk], 0.0f) * fc2_w[kk];
        #pragma unroll
        for (int kk = 0; kk < HID; ++kk) s += fmaxf(hb[kk], 0.0f) * fc2_w[HID + kk];
        s = fmaxf(s, 0.0f);
        out[b] = 1.0f / (1.0f + __expf(-s));
    }
}

extern "C" void kernel_launch(void* const* d_in, const int* in_sizes, int n_in,
                              void* d_out, int out_size, void* d_ws, size_t ws_size,
                              hipStream_t stream)
{
    const float* x        = (const float*)d_in[0];
    const float* w_ih_l0f = (const float*)d_in[1];
    const float* w_hh_l0f = (const float*)d_in[2];
    const float* b_ih_l0f = (const float*)d_in[3];
    const float* b_hh_l0f = (const float*)d_in[4];
    const float* w_ih_l0b = (const float*)d_in[5];
    const float* w_hh_l0b = (const float*)d_in[6];
    const float* b_ih_l0b = (const float*)d_in[7];
    const float* b_hh_l0b = (const float*)d_in[8];
    const float* w_ih_l1f = (const float*)d_in[9];
    const float* w_hh_l1f = (const float*)d_in[10];
    const float* b_ih_l1f = (const float*)d_in[11];
    const float* b_hh_l1f = (const float*)d_in[12];
    const float* w_ih_l1b = (const float*)d_in[13];
    const float* b_ih_l1b = (const float*)d_in[15];
    const float* b_hh_l1b = (const float*)d_in[16];
    const float* fc2_w    = (const float*)d_in[17];
    const float* fc2_b    = (const float*)d_in[18];
    float* out = (float*)d_out;

    __half* h0 = (__half*)d_ws;   // [B,T,50] fp16
    float*  hf = (float*)((char*)d_ws + (size_t)BATCH * T_LEN * 2 * HID * sizeof(__half));

    dim3 g0(BATCH, 2);
    lstm_l0<<<g0, 128, 0, stream>>>(x,
        w_ih_l0f, w_hh_l0f, b_ih_l0f, b_hh_l0f,
        w_ih_l0b, w_hh_l0b, b_ih_l0b, b_hh_l0b, h0);

    lstm_l1f<<<BATCH, 128, 0, stream>>>(h0,
        w_ih_l1f, w_hh_l1f, b_ih_l1f, b_hh_l1f, hf);

    final_kernel<<<BATCH, 128, 0, stream>>>(h0, hf,
        w_ih_l1b, b_ih_l1b, b_hh_l1b, fc2_w, fc2_b, out);
}

// Round 5
// 2473.517 us; speedup vs baseline: 1.0662x; 1.0103x over previous
//
#include <hip/hip_runtime.h>
#include <hip/hip_fp16.h>

#define T_LEN 4096
#define BATCH 256
#define HID   25
#define G4    100
#define CH    16
#define NCHUNK (T_LEN / CH)

#define LOG2E  1.4426950408889634f
#define LOG2E2 2.8853900817779268f

typedef float v2f __attribute__((ext_vector_type(2)));

#define DEV __device__ __forceinline__

#define REP25(M) M(0) M(1) M(2) M(3) M(4) M(5) M(6) M(7) M(8) M(9) \
                 M(10) M(11) M(12) M(13) M(14) M(15) M(16) M(17) M(18) M(19) \
                 M(20) M(21) M(22) M(23) M(24)

DEV float rcpf_(float x){
#if __has_builtin(__builtin_amdgcn_rcpf)
    return __builtin_amdgcn_rcpf(x);
#else
    return 1.0f / x;
#endif
}
DEV float readlane_f(float v, int j){
#if __has_builtin(__builtin_amdgcn_readlane)
    return __int_as_float(__builtin_amdgcn_readlane(__float_as_int(v), j));
#else
    return __shfl(v, j);
#endif
}
DEV v2f fma2(v2f a, v2f b, v2f c){
#if __has_builtin(__builtin_elementwise_fma)
    return __builtin_elementwise_fma(a, b, c);
#else
    v2f r; r.x = fmaf(a.x, b.x, c.x); r.y = fmaf(a.y, b.y, c.y); return r;
#endif
}
DEV float dot2acc(unsigned w, unsigned xv, float acc){
#if __has_builtin(__builtin_amdgcn_fdot2)
    typedef _Float16 h2v __attribute__((ext_vector_type(2)));
    return __builtin_amdgcn_fdot2(__builtin_bit_cast(h2v, w),
                                  __builtin_bit_cast(h2v, xv), acc, false);
#else
    __half2 a = __builtin_bit_cast(__half2, w), b2 = __builtin_bit_cast(__half2, xv);
    float2 fa = __half22float2(a), fb = __half22float2(b2);
    return acc + fa.x * fb.x + fa.y * fb.y;
#endif
}
DEV float sigm_(float x){ return 1.0f - rcpf_(__expf(x) + 1.0f); }
DEV float tanhx_(float x){ return 1.0f - 2.0f * rcpf_(__expf(2.0f * x) + 1.0f); }

// row0-broadcast: every lane receives the value held by lane (lane&31) of the lower half.
#define PLS_ROW0 0
DEV float bcast_row0(float v){
#if __has_builtin(__builtin_amdgcn_permlane32_swap)
    auto r = __builtin_amdgcn_permlane32_swap(__float_as_int(v), __float_as_int(v), false, false);
    return __int_as_float(r[PLS_ROW0]);
#else
    return __shfl(v, (int)(threadIdx.x & 31), 64);
#endif
}

DEV void fence_lgkm(){ asm volatile("s_waitcnt lgkmcnt(0)" ::: "memory"); }
// raw barrier: no vmcnt drain (keeps producer's global loads in flight)
DEV void sync2(){ fence_lgkm(); __builtin_amdgcn_s_barrier(); asm volatile("" ::: "memory"); }

// ---------------- consumer: lane k = gates (i,f), lane 32+k = gates (g,o); cell on upper half ----------------
// xg layout per timestep: [unit k][4] = {i,f,g,o}, bias pre-added, log2e pre-scaled (2*log2e for g)
// Weights live in 25 NAMED v2f registers (no arrays -> no scratch demotion).
template<bool STORE>
DEV void lstm_consumer(const float* __restrict__ w_hh,
                       const float (*xg)[CH][G4], int lane,
                       __half* sptr, long long sstride,
                       float* __restrict__ h_final)
{
    const int k   = ((lane & 31) < HID) ? (lane & 31) : 0;
    const bool up = lane >= 32;
    const int rowA = up ? (2 * HID + k) : k;          // g : i
    const int rowB = up ? (3 * HID + k) : (HID + k);  // o : f
    const float scA = up ? LOG2E2 : LOG2E;

#define DECLW(j) v2f w##j;
    REP25(DECLW)
#undef DECLW
#define LOADW(j) w##j.x = w_hh[rowA * HID + j] * scA; \
                 w##j.y = w_hh[rowB * HID + j] * LOG2E;
    REP25(LOADW)
#undef LOADW

    const float coef = up ? 2.0f : 1.0f;
    const bool store_lane = up && ((lane & 31) < HID);
    float h = 0.0f, cst = 0.0f;
    const int xbyte = k * 16 + (up ? 8 : 0);

    sync2();                                // chunk 0 ready
    for (int c = 0; c < NCHUNK; ++c) {
        const char* buf = (const char*)&xg[c & 1][0][0] + xbyte;
        #pragma unroll
        for (int t = 0; t < CH; ++t) {
            v2f a0 = *(const v2f*)(buf + t * (G4 * 4));   // {xg_A, xg_B} incl. bias
            v2f a1 = {0.f, 0.f}, a2 = {0.f, 0.f}, a3 = {0.f, 0.f};
#define SJ(j, A) { float hs = readlane_f(h, 32 + j); v2f hv; hv.x = hs; hv.y = hs; A = fma2(w##j, hv, A); }
            SJ(0,a0)  SJ(1,a1)  SJ(2,a2)  SJ(3,a3)
            SJ(4,a0)  SJ(5,a1)  SJ(6,a2)  SJ(7,a3)
            SJ(8,a0)  SJ(9,a1)  SJ(10,a2) SJ(11,a3)
            SJ(12,a0) SJ(13,a1) SJ(14,a2) SJ(15,a3)
            SJ(16,a0) SJ(17,a1) SJ(18,a2) SJ(19,a3)
            SJ(20,a0) SJ(21,a1) SJ(22,a2) SJ(23,a3)
            SJ(24,a0)
#undef SJ
            v2f a = (a0 + a1) + (a2 + a3);
            float e0 = __builtin_exp2f(a.x);
            float e1 = __builtin_exp2f(a.y);
            float u0 = 1.0f - coef * rcpf_(e0 + 1.0f);  // lower: sig(i); upper: tanh(g)
            float u1 = 1.0f - rcpf_(e1 + 1.0f);         // lower: sig(f); upper: sig(o)
            float si = bcast_row0(u0);                  // sig(i_k) everywhere
            float sf = bcast_row0(u1);                  // sig(f_k) everywhere
            cst = sf * cst + si * u0;                   // upper: f*c + i*tanh(g)
            float tc = 1.0f - 2.0f * rcpf_(__builtin_exp2f(LOG2E2 * cst) + 1.0f);
            h = u1 * tc;                                // upper: sig(o)*tanh(c)
            if (STORE) {
                if (store_lane) *sptr = __float2half(h);
                sptr += sstride;
            }
        }
        sync2();
    }
    if (!STORE && store_lane) h_final[k] = h;
}

// ================= Layer 0: one block per (batch, dir); wave0=recurrence, wave1=xg producer =================
__global__ __launch_bounds__(128, 1) void lstm_l0(
    const float* __restrict__ x,
    const float* __restrict__ w_ih_f, const float* __restrict__ w_hh_f,
    const float* __restrict__ b_ih_f, const float* __restrict__ b_hh_f,
    const float* __restrict__ w_ih_b, const float* __restrict__ w_hh_b,
    const float* __restrict__ b_ih_b, const float* __restrict__ b_hh_b,
    __half* __restrict__ h0)                       // [B,T,50]
{
    const int b    = blockIdx.x;
    const int dir  = blockIdx.y;
    const int tid  = threadIdx.x;
    const int lane = tid & 63;
    const int wave = tid >> 6;

    const float* w_ih = dir ? w_ih_b : w_ih_f;
    const float* w_hh = dir ? w_hh_b : w_hh_f;
    const float* b_ih = dir ? b_ih_b : b_ih_f;
    const float* b_hh = dir ? b_hh_b : b_hh_f;

    __shared__ __align__(16) float xg[2][CH][G4];  // [t][unit][{i,f,g,o}], scaled, bias included
    __shared__ __align__(16) float xs[CH][28];

    if (wave == 1) {
        // producer: gate rows g0 (0..49) and g1=g0+50; write transposed [unit][4]
        const int g0 = (lane < 50) ? lane : 0;
        const int q0 = g0 / HID, r0 = g0 % HID;
        const int g1 = g0 + 50;
        const float sc0 = LOG2E;
        const float sc1 = (g0 < HID) ? LOG2E2 : LOG2E;   // rows 50..74 = g-gate

#define DECLP(j) float wA##j, wB##j;
        REP25(DECLP)
#undef DECLP
#define LOADP(j) wA##j = w_ih[g0 * HID + j] * sc0; \
                 wB##j = w_ih[g1 * HID + j] * sc1;
        REP25(LOADP)
#undef LOADP
        const float bias0 = (b_ih[g0] + b_hh[g0]) * sc0;
        const float bias1 = (b_ih[g1] + b_hh[g1]) * sc1;

        for (int cc = 0; cc <= NCHUNK; ++cc) {
            if (cc < NCHUNK) {
                const int row0 = dir ? (T_LEN - CH - cc * CH) : (cc * CH);
                const float* src = x + ((size_t)b * T_LEN + row0) * HID;
                #pragma unroll
                for (int i = 0; i < 7; ++i) {
                    int idx = lane + 64 * i;
                    if (idx < CH * HID) {
                        float v = src[idx];
                        int r = idx / HID, col = idx - r * HID;
                        xs[dir ? (CH - 1 - r) : r][col] = v;
                    }
                }
                fence_lgkm();
                float (*dst)[G4] = xg[cc & 1];
                for (int t = 0; t < CH; ++t) {
                    const float* xr = xs[t];
                    float pa0 = bias0, pa1 = 0.f, pa2 = 0.f, pa3 = 0.f;
                    float pb0 = bias1, pb1 = 0.f, pb2 = 0.f, pb3 = 0.f;
#define PJ(j, A, B) { float xv = xr[j]; A = fmaf(wA##j, xv, A); B = fmaf(wB##j, xv, B); }
                    PJ(0,pa0,pb0)  PJ(1,pa1,pb1)  PJ(2,pa2,pb2)  PJ(3,pa3,pb3)
                    PJ(4,pa0,pb0)  PJ(5,pa1,pb1)  PJ(6,pa2,pb2)  PJ(7,pa3,pb3)
                    PJ(8,pa0,pb0)  PJ(9,pa1,pb1)  PJ(10,pa2,pb2) PJ(11,pa3,pb3)
                    PJ(12,pa0,pb0) PJ(13,pa1,pb1) PJ(14,pa2,pb2) PJ(15,pa3,pb3)
                    PJ(16,pa0,pb0) PJ(17,pa1,pb1) PJ(18,pa2,pb2) PJ(19,pa3,pb3)
                    PJ(20,pa0,pb0) PJ(21,pa1,pb1) PJ(22,pa2,pb2) PJ(23,pa3,pb3)
                    PJ(24,pa0,pb0)
#undef PJ
                    if (lane < 50) {
                        dst[t][r0 * 4 + q0]     = (pa0 + pa1) + (pa2 + pa3);
                        dst[t][r0 * 4 + q0 + 2] = (pb0 + pb1) + (pb2 + pb3);
                    }
                }
            }
            sync2();
        }
    } else {
        const int k = ((lane & 31) < HID) ? (lane & 31) : 0;
        __half* sptr = h0 + ((size_t)b * T_LEN + (dir ? (T_LEN - 1) : 0)) * (2 * HID)
                          + (size_t)(dir * HID) + k;
        const long long sstride = dir ? -(long long)(2 * HID) : (long long)(2 * HID);
        lstm_consumer<true>(w_hh, xg, lane, sptr, sstride, nullptr);
    }
}

// ================= Layer 1 forward: one block per batch; only final h kept =================
__global__ __launch_bounds__(128, 1) void lstm_l1f(
    const __half* __restrict__ h0,                 // [B,T,50]
    const float* __restrict__ w_ih, const float* __restrict__ w_hh,
    const float* __restrict__ b_ih, const float* __restrict__ b_hh,
    float* __restrict__ hf)                        // [B,25]
{
    const int b    = blockIdx.x;
    const int tid  = threadIdx.x;
    const int lane = tid & 63;
    const int wave = tid >> 6;

    __shared__ __align__(16) float xg[2][CH][G4];
    __shared__ __align__(16) unsigned xs[CH][28];  // rows of 25 dwords = 50 halves

    if (wave == 1) {
        const int g0 = (lane < 50) ? lane : 0;
        const int q0 = g0 / HID, r0 = g0 % HID;
        const int g1 = g0 + 50;
        const float sc0 = LOG2E;
        const float sc1 = (g0 < HID) ? LOG2E2 : LOG2E;

#define DECLQ(j) unsigned wpA##j, wpB##j;
        REP25(DECLQ)
#undef DECLQ
#define LOADQ(j) { \
        __half2 ha = __floats2half2_rn(w_ih[g0 * (2*HID) + 2*j] * sc0, w_ih[g0 * (2*HID) + 2*j + 1] * sc0); \
        __half2 hc = __floats2half2_rn(w_ih[g1 * (2*HID) + 2*j] * sc1, w_ih[g1 * (2*HID) + 2*j + 1] * sc1); \
        wpA##j = __builtin_bit_cast(unsigned, ha); \
        wpB##j = __builtin_bit_cast(unsigned, hc); }
        REP25(LOADQ)
#undef LOADQ
        const float bias0 = (b_ih[g0] + b_hh[g0]) * sc0;
        const float bias1 = (b_ih[g1] + b_hh[g1]) * sc1;
        const unsigned* hsrc = (const unsigned*)h0;

        for (int cc = 0; cc <= NCHUNK; ++cc) {
            if (cc < NCHUNK) {
                const unsigned* src = hsrc + ((size_t)b * T_LEN + cc * CH) * HID;
                #pragma unroll
                for (int i = 0; i < 7; ++i) {
                    int idx = lane + 64 * i;
                    if (idx < CH * HID) {
                        unsigned v = src[idx];
                        int r = idx / HID, col = idx - r * HID;
                        xs[r][col] = v;
                    }
                }
                fence_lgkm();
                float (*dst)[G4] = xg[cc & 1];
                for (int t = 0; t < CH; ++t) {
                    const unsigned* xr = xs[t];
                    float pa0 = bias0, pa1 = 0.f, pa2 = 0.f, pa3 = 0.f;
                    float pb0 = bias1, pb1 = 0.f, pb2 = 0.f, pb3 = 0.f;
#define QJ(j, A, B) { unsigned xv = xr[j]; A = dot2acc(wpA##j, xv, A); B = dot2acc(wpB##j, xv, B); }
                    QJ(0,pa0,pb0)  QJ(1,pa1,pb1)  QJ(2,pa2,pb2)  QJ(3,pa3,pb3)
                    QJ(4,pa0,pb0)  QJ(5,pa1,pb1)  QJ(6,pa2,pb2)  QJ(7,pa3,pb3)
                    QJ(8,pa0,pb0)  QJ(9,pa1,pb1)  QJ(10,pa2,pb2) QJ(11,pa3,pb3)
                    QJ(12,pa0,pb0) QJ(13,pa1,pb1) QJ(14,pa2,pb2) QJ(15,pa3,pb3)
                    QJ(16,pa0,pb0) QJ(17,pa1,pb1) QJ(18,pa2,pb2) QJ(19,pa3,pb3)
                    QJ(20,pa0,pb0) QJ(21,pa1,pb1) QJ(22,pa2,pb2) QJ(23,pa3,pb3)
                    QJ(24,pa0,pb0)
#undef QJ
                    if (lane < 50) {
                        dst[t][r0 * 4 + q0]     = (pa0 + pa1) + (pa2 + pa3);
                        dst[t][r0 * 4 + q0 + 2] = (pb0 + pb1) + (pb2 + pb3);
                    }
                }
            }
            sync2();
        }
    } else {
        lstm_consumer<false>(w_hh, xg, lane, nullptr, 0, hf + (size_t)b * HID);
    }
}

// ================= Layer 1 backward (1 step from zero state) + FC head =================
__global__ __launch_bounds__(128) void final_kernel(
    const __half* __restrict__ h0,
    const float* __restrict__ hf,
    const float* __restrict__ w_ih1b,
    const float* __restrict__ b_ih1b, const float* __restrict__ b_hh1b,
    const float* __restrict__ fc2_w, const float* __restrict__ fc2_b,
    float* __restrict__ out)
{
    const int b   = blockIdx.x;
    const int tid = threadIdx.x;

    __shared__ float inb[2 * HID];
    __shared__ float act[G4];
    __shared__ float hb[HID];

    if (tid < HID) {
        const __half2* rr = (const __half2*)(h0 + ((size_t)b * T_LEN + (T_LEN - 1)) * (2 * HID));
        float2 v = __half22float2(rr[tid]);
        inb[2 * tid] = v.x; inb[2 * tid + 1] = v.y;
    }
    __syncthreads();

    if (tid < G4) {
        float g = b_ih1b[tid] + b_hh1b[tid];
        #pragma unroll
        for (int kk = 0; kk < 2 * HID; ++kk) g += w_ih1b[tid * (2 * HID) + kk] * inb[kk];
        act[tid] = (tid >= 2 * HID && tid < 3 * HID) ? tanhx_(g) : sigm_(g);
    }
    __syncthreads();

    if (tid < HID) {
        float c = act[tid] * act[2 * HID + tid];   // c0 = 0
        hb[tid] = act[3 * HID + tid] * tanhx_(c);
    }
    __syncthreads();

    if (tid == 0) {
        float s = fc2_b[0];
        #pragma unroll
        for (int kk = 0; kk < HID; ++kk) s += fmaxf(hf[b * HID + kk], 0.0f) * fc2_w[kk];
        #pragma unroll
        for (int kk = 0; kk < HID; ++kk) s += fmaxf(hb[kk], 0.0f) * fc2_w[HID + kk];
        s = fmaxf(s, 0.0f);
        out[b] = 1.0f / (1.0f + __expf(-s));
    }
}

extern "C" void kernel_launch(void* const* d_in, const int* in_sizes, int n_in,
                              void* d_out, int out_size, void* d_ws, size_t ws_size,
                              hipStream_t stream)
{
    const float* x        = (const float*)d_in[0];
    const float* w_ih_l0f = (const float*)d_in[1];
    const float* w_hh_l0f = (const float*)d_in[2];
    const float* b_ih_l0f = (const float*)d_in[3];
    const float* b_hh_l0f = (const float*)d_in[4];
    const float* w_ih_l0b = (const float*)d_in[5];
    const float* w_hh_l0b = (const float*)d_in[6];
    const float* b_ih_l0b = (const float*)d_in[7];
    const float* b_hh_l0b = (const float*)d_in[8];
    const float* w_ih_l1f = (const float*)d_in[9];
    const float* w_hh_l1f = (const float*)d_in[10];
    const float* b_ih_l1f = (const float*)d_in[11];
    const float* b_hh_l1f = (const float*)d_in[12];
    const float* w_ih_l1b = (const float*)d_in[13];
    const float* b_ih_l1b = (const float*)d_in[15];
    const float* b_hh_l1b = (const float*)d_in[16];
    const float* fc2_w    = (const float*)d_in[17];
    const float* fc2_b    = (const float*)d_in[18];
    float* out = (float*)d_out;

    __half* h0 = (__half*)d_ws;   // [B,T,50] fp16
    float*  hf = (float*)((char*)d_ws + (size_t)BATCH * T_LEN * 2 * HID * sizeof(__half));

    dim3 g0(BATCH, 2);
    lstm_l0<<<g0, 128, 0, stream>>>(x,
        w_ih_l0f, w_hh_l0f, b_ih_l0f, b_hh_l0f,
        w_ih_l0b, w_hh_l0b, b_ih_l0b, b_hh_l0b, h0);

    lstm_l1f<<<BATCH, 128, 0, stream>>>(h0,
        w_ih_l1f, w_hh_l1f, b_ih_l1f, b_hh_l1f, hf);

    final_kernel<<<BATCH, 128, 0, stream>>>(h0, hf,
        w_ih_l1b, b_ih_l1b, b_hh_l1b, fc2_w, fc2_b, out);
}

// Round 6
// 2294.403 us; speedup vs baseline: 1.1494x; 1.0781x over previous
//
#include <hip/hip_runtime.h>
#include <hip/hip_fp16.h>

#define T_LEN 4096
#define BATCH 256
#define HID   25
#define G4    100
#define NSEG  16
#define SEG_T (T_LEN / NSEG)   // 256
#define TG    16
#define NTG   (SEG_T / TG)     // 16

#define LOG2E  1.4426950408889634f
#define LOG2E2 2.8853900817779268f

typedef float v2f __attribute__((ext_vector_type(2)));
#define DEV __device__ __forceinline__

#define REP25(M) M(0) M(1) M(2) M(3) M(4) M(5) M(6) M(7) M(8) M(9) \
                 M(10) M(11) M(12) M(13) M(14) M(15) M(16) M(17) M(18) M(19) \
                 M(20) M(21) M(22) M(23) M(24)

DEV float rcpf_(float x){
#if __has_builtin(__builtin_amdgcn_rcpf)
    return __builtin_amdgcn_rcpf(x);
#else
    return 1.0f / x;
#endif
}
DEV float readlane_f(float v, int j){
#if __has_builtin(__builtin_amdgcn_readlane)
    return __int_as_float(__builtin_amdgcn_readlane(__float_as_int(v), j));
#else
    return __shfl(v, j);
#endif
}
DEV v2f fma2(v2f a, v2f b, v2f c){
#if __has_builtin(__builtin_elementwise_fma)
    return __builtin_elementwise_fma(a, b, c);
#else
    v2f r; r.x = fmaf(a.x, b.x, c.x); r.y = fmaf(a.y, b.y, c.y); return r;
#endif
}
DEV float dot2acc(unsigned w, unsigned xv, float acc){
#if __has_builtin(__builtin_amdgcn_fdot2)
    typedef _Float16 h2v __attribute__((ext_vector_type(2)));
    return __builtin_amdgcn_fdot2(__builtin_bit_cast(h2v, w),
                                  __builtin_bit_cast(h2v, xv), acc, false);
#else
    __half2 a = __builtin_bit_cast(__half2, w), b2 = __builtin_bit_cast(__half2, xv);
    float2 fa = __half22float2(a), fb = __half22float2(b2);
    return acc + fa.x * fb.x + fa.y * fb.y;
#endif
}
DEV float sigm_(float x){ return 1.0f - rcpf_(__expf(x) + 1.0f); }
DEV float tanhx_(float x){ return 1.0f - 2.0f * rcpf_(__expf(2.0f * x) + 1.0f); }

// row0-broadcast: every lane receives the value held by lane (lane&31) of the LOWER half.
// Verified on HW (rounds 4/5, absmax 0).
DEV float bcast_row0(float v){
#if __has_builtin(__builtin_amdgcn_permlane32_swap)
    auto r = __builtin_amdgcn_permlane32_swap(__float_as_int(v), __float_as_int(v), false, false);
    return __int_as_float(r[0]);
#else
    return __shfl(v, (int)(threadIdx.x & 31), 64);
#endif
}

// ================= recurrence block: one wave, zero LDS, zero barriers =================
// xg[t][unit k][{i,f,g,o}] fp16, bias-added, log2e-prescaled (2*log2e for g rows).
// lane k (<32): gates (i,f); lane 32+k: gates (g,o). Cell update lane-local on upper half.
template<bool STORE>
DEV void rec_block(const __half* __restrict__ xg,
                   const float* __restrict__ w_hh,
                   __half* __restrict__ h0out,
                   float* __restrict__ stH, float* __restrict__ stC,
                   int b, int dir, int seg, int first)
{
    const int lane = threadIdx.x;          // caller guarantees < 64
    const int k    = ((lane & 31) < HID) ? (lane & 31) : 0;
    const bool up  = lane >= 32;
    const int rowA = up ? (2 * HID + k) : k;          // g : i
    const int rowB = up ? (3 * HID + k) : (HID + k);  // o : f
    const float scA  = up ? LOG2E2 : LOG2E;
    const float coef = up ? 2.0f : 1.0f;

#define DECLW(j) v2f w##j;
    REP25(DECLW)
#undef DECLW
#define LOADW(j) w##j.x = w_hh[rowA * HID + j] * scA; \
                 w##j.y = w_hh[rowB * HID + j] * LOG2E;
    REP25(LOADW)
#undef LOADW

    const int sidx = (dir * BATCH + b) * 32 + k;
    float h = 0.0f, cst = 0.0f;
    if (!first) { h = stH[sidx]; cst = stC[sidx]; }

    const unsigned* src = (const unsigned*)xg + (size_t)b * SEG_T * (G4 / 2)
                        + (k * 2 + (up ? 1 : 0));
    unsigned pf[8];
    #pragma unroll
    for (int s = 0; s < 8; ++s) pf[s] = src[s * (G4 / 2)];
    const unsigned* pnext = src + 8 * (G4 / 2);

    __half* sptr = nullptr;
    long long sstride = 0;
    if (STORE) {
        const int tstart = dir ? (seg * SEG_T + SEG_T - 1) : (seg * SEG_T);
        sptr = h0out + ((size_t)b * T_LEN + tstart) * (2 * HID) + dir * HID + k;
        sstride = dir ? -(long long)(2 * HID) : (long long)(2 * HID);
    }
    const bool store_lane = up && ((lane & 31) < HID);

    for (int tb = 0; tb < SEG_T; tb += 8) {
        #pragma unroll
        for (int s = 0; s < 8; ++s) {
            const unsigned cur = pf[s];
            pf[s] = pnext[s * (G4 / 2)];             // prefetch t+8 (pad absorbs tail overread)
            const __half2 hx = __builtin_bit_cast(__half2, cur);
            const float2 xv = __half22float2(hx);
            v2f a0; a0.x = xv.x; a0.y = xv.y;
            v2f a1 = {0.f, 0.f}, a2 = {0.f, 0.f}, a3 = {0.f, 0.f};
#define SJ(j, A) { float hs = readlane_f(h, 32 + j); v2f hv; hv.x = hs; hv.y = hs; A = fma2(w##j, hv, A); }
            SJ(0,a0)  SJ(1,a1)  SJ(2,a2)  SJ(3,a3)
            SJ(4,a0)  SJ(5,a1)  SJ(6,a2)  SJ(7,a3)
            SJ(8,a0)  SJ(9,a1)  SJ(10,a2) SJ(11,a3)
            SJ(12,a0) SJ(13,a1) SJ(14,a2) SJ(15,a3)
            SJ(16,a0) SJ(17,a1) SJ(18,a2) SJ(19,a3)
            SJ(20,a0) SJ(21,a1) SJ(22,a2) SJ(23,a3)
            SJ(24,a0)
#undef SJ
            v2f a = (a0 + a1) + (a2 + a3);
            float e0 = __builtin_exp2f(a.x);
            float e1 = __builtin_exp2f(a.y);
            float u0 = 1.0f - coef * rcpf_(e0 + 1.0f);   // lower: sig(i); upper: tanh(g)
            float u1 = 1.0f - rcpf_(e1 + 1.0f);          // lower: sig(f); upper: sig(o)
            float si = bcast_row0(u0);
            float sf = bcast_row0(u1);
            cst = sf * cst + si * u0;                    // upper: f*c + i*tanh(g)
            float tc = 1.0f - 2.0f * rcpf_(__builtin_exp2f(LOG2E2 * cst) + 1.0f);
            h = u1 * tc;                                 // upper: sig(o)*tanh(c)
            if (STORE) {
                if (store_lane) *sptr = __float2half(h);
                sptr += sstride;
            }
        }
        pnext += 8 * (G4 / 2);
    }
    if (store_lane) { stH[sidx] = h; stC[sidx] = cst; }
}

// ================= xg GEMM blocks (throughput work, off the critical path) =================
DEV void gemm_l0_block(float* xs, __half* og,
                       const float* __restrict__ x,
                       const float* __restrict__ w_ih, const float* __restrict__ b_ih,
                       const float* __restrict__ b_hh,
                       __half* __restrict__ xgdst, int b, int by, int dir, int seg)
{
    const int tid = threadIdx.x;
    const int t0 = seg * SEG_T + by * TG;
    const float* src = x + ((size_t)b * T_LEN + t0) * HID;
    #pragma unroll
    for (int i = 0; i < 4; ++i) { int idx = tid + 128 * i; if (idx < TG * HID) xs[idx] = src[idx]; }
    __syncthreads();
    if (tid < G4) {
        const int g = tid;
        const float sc = (g >= 2 * HID && g < 3 * HID) ? LOG2E2 : LOG2E;
        float w[HID];
        #pragma unroll
        for (int j = 0; j < HID; ++j) w[j] = w_ih[g * HID + j] * sc;
        const float bias = (b_ih[g] + b_hh[g]) * sc;
        const int pos = (g % HID) * 4 + (g / HID);
        for (int t = 0; t < TG; ++t) {
            const float* xr = xs + t * HID;
            float a0 = bias, a1 = 0.f, a2 = 0.f, a3 = 0.f;
            #pragma unroll
            for (int j = 0; j < 24; j += 4) {
                a0 = fmaf(w[j],     xr[j],     a0);
                a1 = fmaf(w[j + 1], xr[j + 1], a1);
                a2 = fmaf(w[j + 2], xr[j + 2], a2);
                a3 = fmaf(w[j + 3], xr[j + 3], a3);
            }
            a0 = fmaf(w[24], xr[24], a0);
            const int orow = dir ? (TG - 1 - t) : t;    // bwd buffer is time-reversed
            og[orow * G4 + pos] = __float2half((a0 + a1) + (a2 + a3));
        }
    }
    __syncthreads();
    const int rowbase = (dir ? (NTG - 1 - by) : by) * TG;
    unsigned* dst = (unsigned*)xgdst + ((size_t)b * SEG_T + rowbase) * (G4 / 2);
    const unsigned* ogu = (const unsigned*)og;
    #pragma unroll
    for (int i = 0; i < 7; ++i) { int idx = tid + 128 * i; if (idx < TG * (G4 / 2)) dst[idx] = ogu[idx]; }
}

DEV void gemm_l1_block(unsigned* xsu, __half* og,
                       const __half* __restrict__ h0,
                       const float* __restrict__ w_ih, const float* __restrict__ b_ih,
                       const float* __restrict__ b_hh,
                       __half* __restrict__ xgdst, int b, int by, int seg)
{
    const int tid = threadIdx.x;
    const int t0 = seg * SEG_T + by * TG;
    const unsigned* src = (const unsigned*)h0 + ((size_t)b * T_LEN + t0) * HID;
    #pragma unroll
    for (int i = 0; i < 4; ++i) { int idx = tid + 128 * i; if (idx < TG * HID) xsu[idx] = src[idx]; }
    __syncthreads();
    if (tid < G4) {
        const int g = tid;
        const float sc = (g >= 2 * HID && g < 3 * HID) ? LOG2E2 : LOG2E;
        unsigned wp[HID];
        #pragma unroll
        for (int j = 0; j < HID; ++j) {
            __half2 hw = __floats2half2_rn(w_ih[g * (2 * HID) + 2 * j] * sc,
                                           w_ih[g * (2 * HID) + 2 * j + 1] * sc);
            wp[j] = __builtin_bit_cast(unsigned, hw);
        }
        const float bias = (b_ih[g] + b_hh[g]) * sc;
        const int pos = (g % HID) * 4 + (g / HID);
        for (int t = 0; t < TG; ++t) {
            const unsigned* xr = xsu + t * HID;
            float a0 = bias, a1 = 0.f, a2 = 0.f, a3 = 0.f;
            #pragma unroll
            for (int j = 0; j < 24; j += 4) {
                a0 = dot2acc(wp[j],     xr[j],     a0);
                a1 = dot2acc(wp[j + 1], xr[j + 1], a1);
                a2 = dot2acc(wp[j + 2], xr[j + 2], a2);
                a3 = dot2acc(wp[j + 3], xr[j + 3], a3);
            }
            a0 = dot2acc(wp[24], xr[24], a0);
            og[t * G4 + pos] = __float2half((a0 + a1) + (a2 + a3));
        }
    }
    __syncthreads();
    unsigned* dst = (unsigned*)xgdst + ((size_t)b * SEG_T + (size_t)by * TG) * (G4 / 2);
    const unsigned* ogu = (const unsigned*)og;
    #pragma unroll
    for (int i = 0; i < 7; ++i) { int idx = tid + 128 * i; if (idx < TG * (G4 / 2)) dst[idx] = ogu[idx]; }
}

// ================= combined launches: rec(seg s) blocks + gemm(seg s+1) blocks =================
__global__ __launch_bounds__(128, 1) void combo_l0(
    const float* __restrict__ x,
    const float* __restrict__ w_ih_f, const float* __restrict__ b_ih_f, const float* __restrict__ b_hh_f,
    const float* __restrict__ w_ih_b, const float* __restrict__ b_ih_b, const float* __restrict__ b_hh_b,
    const float* __restrict__ w_hh_f, const float* __restrict__ w_hh_b,
    const __half* __restrict__ xg_rd_f, const __half* __restrict__ xg_rd_b,
    __half* __restrict__ xg_wr_f, __half* __restrict__ xg_wr_b,
    __half* __restrict__ h0, float* __restrict__ stH, float* __restrict__ stC,
    int seg_f, int seg_b, int seg_f_next, int seg_b_next, int first)
{
    __shared__ float  xs[TG * HID];
    __shared__ __half og[TG * G4];
    const int bid = blockIdx.x;
    if (bid < 2 * BATCH) {
        if (threadIdx.x >= 64) return;
        const int b = bid & (BATCH - 1);
        const int dir = bid >> 8;
        rec_block<true>(dir ? xg_rd_b : xg_rd_f, dir ? w_hh_b : w_hh_f,
                        h0, stH, stC, b, dir, dir ? seg_b : seg_f, first);
    } else {
        const int g = bid - 2 * BATCH;
        const int b = g & (BATCH - 1);
        const int r = g >> 8;               // 0..2*NTG-1
        const int by = r & (NTG - 1);
        const int dir = r >> 4;             // NTG == 16
        const int seg = dir ? seg_b_next : seg_f_next;
        if (seg < 0) return;
        gemm_l0_block(xs, og, x,
                      dir ? w_ih_b : w_ih_f, dir ? b_ih_b : b_ih_f, dir ? b_hh_b : b_hh_f,
                      dir ? xg_wr_b : xg_wr_f, b, by, dir, seg);
    }
}

__global__ __launch_bounds__(128, 1) void combo_l1(
    const __half* __restrict__ h0,
    const float* __restrict__ w_ih, const float* __restrict__ b_ih, const float* __restrict__ b_hh,
    const float* __restrict__ w_hh,
    const __half* __restrict__ xg_rd, __half* __restrict__ xg_wr,
    float* __restrict__ stH, float* __restrict__ stC,
    int seg, int seg_next, int first)
{
    __shared__ unsigned xsu[TG * HID];
    __shared__ __half   og[TG * G4];
    const int bid = blockIdx.x;
    if (bid < BATCH) {
        if (threadIdx.x >= 64) return;
        rec_block<false>(xg_rd, w_hh, nullptr, stH, stC, bid, 0, seg, first);
    } else {
        const int g = bid - BATCH;
        const int b = g & (BATCH - 1);
        const int by = g >> 8;              // 0..NTG-1
        if (seg_next < 0) return;
        gemm_l1_block(xsu, og, h0, w_ih, b_ih, b_hh, xg_wr, b, by, seg_next);
    }
}

// prologue gemm-only launches
__global__ __launch_bounds__(128) void gemm_l0_pro(
    const float* __restrict__ x,
    const float* __restrict__ w_ih_f, const float* __restrict__ b_ih_f, const float* __restrict__ b_hh_f,
    const float* __restrict__ w_ih_b, const float* __restrict__ b_ih_b, const float* __restrict__ b_hh_b,
    __half* __restrict__ xgf, __half* __restrict__ xgb)
{
    __shared__ float  xs[TG * HID];
    __shared__ __half og[TG * G4];
    const int dir = blockIdx.z;
    gemm_l0_block(xs, og, x,
                  dir ? w_ih_b : w_ih_f, dir ? b_ih_b : b_ih_f, dir ? b_hh_b : b_hh_f,
                  dir ? xgb : xgf, blockIdx.x, blockIdx.y, dir, dir ? (NSEG - 1) : 0);
}

__global__ __launch_bounds__(128) void gemm_l1_pro(
    const __half* __restrict__ h0,
    const float* __restrict__ w_ih, const float* __restrict__ b_ih, const float* __restrict__ b_hh,
    __half* __restrict__ xg)
{
    __shared__ unsigned xsu[TG * HID];
    __shared__ __half   og[TG * G4];
    gemm_l1_block(xsu, og, h0, w_ih, b_ih, b_hh, xg, blockIdx.x, blockIdx.y, 0);
}

// ================= Layer 1 backward (1 step from zero state) + FC head =================
__global__ __launch_bounds__(128) void final_kernel(
    const __half* __restrict__ h0,
    const float* __restrict__ stH1,
    const float* __restrict__ w_ih1b,
    const float* __restrict__ b_ih1b, const float* __restrict__ b_hh1b,
    const float* __restrict__ fc2_w, const float* __restrict__ fc2_b,
    float* __restrict__ out)
{
    const int b   = blockIdx.x;
    const int tid = threadIdx.x;

    __shared__ float inb[2 * HID];
    __shared__ float act[G4];
    __shared__ float hb[HID];

    if (tid < HID) {
        const __half2* rr = (const __half2*)(h0 + ((size_t)b * T_LEN + (T_LEN - 1)) * (2 * HID));
        float2 v = __half22float2(rr[tid]);
        inb[2 * tid] = v.x; inb[2 * tid + 1] = v.y;
    }
    __syncthreads();

    if (tid < G4) {
        float g = b_ih1b[tid] + b_hh1b[tid];
        #pragma unroll
        for (int kk = 0; kk < 2 * HID; ++kk) g += w_ih1b[tid * (2 * HID) + kk] * inb[kk];
        act[tid] = (tid >= 2 * HID && tid < 3 * HID) ? tanhx_(g) : sigm_(g);
    }
    __syncthreads();

    if (tid < HID) {
        float c = act[tid] * act[2 * HID + tid];   // c0 = 0
        hb[tid] = act[3 * HID + tid] * tanhx_(c);
    }
    __syncthreads();

    if (tid == 0) {
        float s = fc2_b[0];
        #pragma unroll
        for (int kk = 0; kk < HID; ++kk) s += fmaxf(stH1[b * 32 + kk], 0.0f) * fc2_w[kk];
        #pragma unroll
        for (int kk = 0; kk < HID; ++kk) s += fmaxf(hb[kk], 0.0f) * fc2_w[HID + kk];
        s = fmaxf(s, 0.0f);
        out[b] = 1.0f / (1.0f + __expf(-s));
    }
}

extern "C" void kernel_launch(void* const* d_in, const int* in_sizes, int n_in,
                              void* d_out, int out_size, void* d_ws, size_t ws_size,
                              hipStream_t stream)
{
    const float* x        = (const float*)d_in[0];
    const float* w_ih_l0f = (const float*)d_in[1];
    const float* w_hh_l0f = (const float*)d_in[2];
    const float* b_ih_l0f = (const float*)d_in[3];
    const float* b_hh_l0f = (const float*)d_in[4];
    const float* w_ih_l0b = (const float*)d_in[5];
    const float* w_hh_l0b = (const float*)d_in[6];
    const float* b_ih_l0b = (const float*)d_in[7];
    const float* b_hh_l0b = (const float*)d_in[8];
    const float* w_ih_l1f = (const float*)d_in[9];
    const float* w_hh_l1f = (const float*)d_in[10];
    const float* b_ih_l1f = (const float*)d_in[11];
    const float* b_hh_l1f = (const float*)d_in[12];
    const float* w_ih_l1b = (const float*)d_in[13];
    const float* b_ih_l1b = (const float*)d_in[15];
    const float* b_hh_l1b = (const float*)d_in[16];
    const float* fc2_w    = (const float*)d_in[17];
    const float* fc2_b    = (const float*)d_in[18];
    float* out = (float*)d_out;

    // ---- workspace layout (~158 MB) ----
    const size_t H0B  = (size_t)BATCH * T_LEN * 2 * HID * sizeof(__half);   // 104,857,600
    const size_t XSEG = (size_t)BATCH * SEG_T * G4 * sizeof(__half);        // 13,107,200
    const size_t PAD  = 4096;
    char* p = (char*)d_ws;
    __half* h0 = (__half*)p;                 p += H0B;
    __half* xgf0 = (__half*)p;               p += XSEG + PAD;
    __half* xgf1 = (__half*)p;               p += XSEG + PAD;
    __half* xgb0 = (__half*)p;               p += XSEG + PAD;
    __half* xgb1 = (__half*)p;               p += XSEG + PAD;
    float* stH0 = (float*)p;                 p += 2 * BATCH * 32 * sizeof(float);
    float* stC0 = (float*)p;                 p += 2 * BATCH * 32 * sizeof(float);
    float* stH1 = (float*)p;                 p += BATCH * 32 * sizeof(float);
    float* stC1 = (float*)p;

    __half* xgf[2] = { xgf0, xgf1 };
    __half* xgb[2] = { xgb0, xgb1 };

    // -------- layer 0 --------
    gemm_l0_pro<<<dim3(BATCH, NTG, 2), 128, 0, stream>>>(
        x, w_ih_l0f, b_ih_l0f, b_hh_l0f, w_ih_l0b, b_ih_l0b, b_hh_l0b, xgf[0], xgb[0]);
    for (int s = 0; s < NSEG; ++s) {
        const int sn = s + 1;
        combo_l0<<<2 * BATCH + BATCH * 2 * NTG, 128, 0, stream>>>(
            x, w_ih_l0f, b_ih_l0f, b_hh_l0f, w_ih_l0b, b_ih_l0b, b_hh_l0b,
            w_hh_l0f, w_hh_l0b,
            xgf[s & 1], xgb[s & 1], xgf[sn & 1], xgb[sn & 1],
            h0, stH0, stC0,
            s, NSEG - 1 - s,
            (sn < NSEG) ? sn : -1, (sn < NSEG) ? (NSEG - 1 - sn) : -1,
            s == 0 ? 1 : 0);
    }
    // -------- layer 1 forward --------
    gemm_l1_pro<<<dim3(BATCH, NTG), 128, 0, stream>>>(
        h0, w_ih_l1f, b_ih_l1f, b_hh_l1f, xgf[0]);
    for (int s = 0; s < NSEG; ++s) {
        const int sn = s + 1;
        combo_l1<<<BATCH + BATCH * NTG, 128, 0, stream>>>(
            h0, w_ih_l1f, b_ih_l1f, b_hh_l1f, w_hh_l1f,
            xgf[s & 1], xgf[sn & 1],
            stH1, stC1,
            s, (sn < NSEG) ? sn : -1, s == 0 ? 1 : 0);
    }
    // -------- layer 1 backward single step + head --------
    final_kernel<<<BATCH, 128, 0, stream>>>(
        h0, stH1, w_ih_l1b, b_ih_l1b, b_hh_l1b, fc2_w, fc2_b, out);
}

// Round 7
// 2285.038 us; speedup vs baseline: 1.1541x; 1.0041x over previous
//
#include <hip/hip_runtime.h>
#include <hip/hip_fp16.h>

#define T_LEN 4096
#define BATCH 256
#define HID   25
#define G4    100
#define NSEG  16
#define SEG_T (T_LEN / NSEG)   // 256
#define TG    16
#define NTG   (SEG_T / TG)     // 16

#define LOG2E  1.4426950408889634f
#define LOG2E2 2.8853900817779268f

#define DEV __device__ __forceinline__

#define REP13(M) M(0) M(1) M(2) M(3) M(4) M(5) M(6) M(7) M(8) M(9) M(10) M(11) M(12)

DEV float rcpf_(float x){
#if __has_builtin(__builtin_amdgcn_rcpf)
    return __builtin_amdgcn_rcpf(x);
#else
    return 1.0f / x;
#endif
}
DEV float readlane_f(float v, int j){
#if __has_builtin(__builtin_amdgcn_readlane)
    return __int_as_float(__builtin_amdgcn_readlane(__float_as_int(v), j));
#else
    return __shfl(v, j);
#endif
}
DEV unsigned pkrtz_(float a, float b){
#if __has_builtin(__builtin_amdgcn_cvt_pkrtz)
    return __builtin_bit_cast(unsigned, __builtin_amdgcn_cvt_pkrtz(a, b));
#else
    __half2 h = __floats2half2_rn(a, b);
    return __builtin_bit_cast(unsigned, h);
#endif
}
DEV float dot2acc(unsigned w, unsigned xv, float acc){
#if __has_builtin(__builtin_amdgcn_fdot2)
    typedef _Float16 h2v __attribute__((ext_vector_type(2)));
    return __builtin_amdgcn_fdot2(__builtin_bit_cast(h2v, w),
                                  __builtin_bit_cast(h2v, xv), acc, false);
#else
    __half2 a = __builtin_bit_cast(__half2, w), b2 = __builtin_bit_cast(__half2, xv);
    float2 fa = __half22float2(a), fb = __half22float2(b2);
    return acc + fa.x * fb.x + fa.y * fb.y;
#endif
}
DEV float sigm_(float x){ return 1.0f - rcpf_(__expf(x) + 1.0f); }
DEV float tanhx_(float x){ return 1.0f - 2.0f * rcpf_(__expf(2.0f * x) + 1.0f); }

// row0-broadcast: every lane receives the value held by lane (lane&31) of the LOWER half.
// Verified on HW (rounds 4/5/6, absmax 0).
DEV float bcast_row0(float v){
#if __has_builtin(__builtin_amdgcn_permlane32_swap)
    auto r = __builtin_amdgcn_permlane32_swap(__float_as_int(v), __float_as_int(v), false, false);
    return __int_as_float(r[0]);
#else
    return __shfl(v, (int)(threadIdx.x & 31), 64);
#endif
}

// ================= recurrence block: one wave, zero LDS, zero barriers =================
// xg[t][unit k][{i,f,g,o}] fp16, bias-added, log2e-prescaled (2*log2e for g rows).
// lane k (<32): gates (i,f); lane 32+k: gates (g,o). Cell update lane-local on upper half.
// Recurrent weights: 26 packed-fp16 VGPRs (13 half2 per gate), pinned across the loop.
template<bool STORE>
DEV void rec_block(const __half* __restrict__ xg,
                   const float* __restrict__ w_hh,
                   __half* __restrict__ h0out,
                   float* __restrict__ stH, float* __restrict__ stC,
                   int b, int dir, int seg, int first)
{
    const int lane = threadIdx.x;          // caller guarantees < 64
    const int k    = ((lane & 31) < HID) ? (lane & 31) : 0;
    const bool up  = lane >= 32;
    const int rowA = up ? (2 * HID + k) : k;          // g : i
    const int rowB = up ? (3 * HID + k) : (HID + k);  // o : f
    const float scA  = up ? LOG2E2 : LOG2E;
    const float coef = up ? 2.0f : 1.0f;

#define DECLW(m) unsigned wA##m, wB##m;
    REP13(DECLW)
#undef DECLW
#define LOADW(m) { \
    const bool tl = (2 * m + 1 < HID); \
    float a0 = w_hh[rowA * HID + 2 * m] * scA; \
    float a1 = tl ? w_hh[rowA * HID + 2 * m + 1] * scA : 0.0f; \
    float b0 = w_hh[rowB * HID + 2 * m] * LOG2E; \
    float b1 = tl ? w_hh[rowB * HID + 2 * m + 1] * LOG2E : 0.0f; \
    wA##m = pkrtz_(a0, a1); \
    wB##m = pkrtz_(b0, b1); }
    REP13(LOADW)
#undef LOADW

    const int sidx = (dir * BATCH + b) * 32 + k;
    float h = 0.0f, cst = 0.0f;
    if (!first) { h = stH[sidx]; cst = stC[sidx]; }

    const unsigned* src = (const unsigned*)xg + (size_t)b * SEG_T * (G4 / 2)
                        + (k * 2 + (up ? 1 : 0));
    unsigned pf[8];
    #pragma unroll
    for (int s = 0; s < 8; ++s) pf[s] = src[s * (G4 / 2)];
    const unsigned* pnext = src + 8 * (G4 / 2);

    __half* sptr = nullptr;
    long long sstride = 0;
    if (STORE) {
        const int tstart = dir ? (seg * SEG_T + SEG_T - 1) : (seg * SEG_T);
        sptr = h0out + ((size_t)b * T_LEN + tstart) * (2 * HID) + dir * HID + k;
        sstride = dir ? -(long long)(2 * HID) : (long long)(2 * HID);
    }
    const bool store_lane = up && ((lane & 31) < HID);

    for (int tb = 0; tb < SEG_T; tb += 8) {
        // pin the 26 packed weights live across the back-edge (no instruction cost):
        asm volatile("" :
            "+v"(wA0), "+v"(wA1), "+v"(wA2), "+v"(wA3), "+v"(wA4), "+v"(wA5),
            "+v"(wA6), "+v"(wA7), "+v"(wA8), "+v"(wA9), "+v"(wA10), "+v"(wA11), "+v"(wA12),
            "+v"(wB0), "+v"(wB1), "+v"(wB2), "+v"(wB3), "+v"(wB4), "+v"(wB5),
            "+v"(wB6), "+v"(wB7), "+v"(wB8), "+v"(wB9), "+v"(wB10), "+v"(wB11), "+v"(wB12));
        #pragma unroll
        for (int s = 0; s < 8; ++s) {
            const unsigned cur = pf[s];
            pf[s] = pnext[s * (G4 / 2)];             // prefetch t+8 (pad absorbs tail overread)
            const __half2 hx = __builtin_bit_cast(__half2, cur);
            const float2 xv = __half22float2(hx);
            // pack h into 13 half2 (shared by both gate dots)
#define HPACK(m) unsigned hp##m; { \
            float ha = readlane_f(h, 32 + 2 * m); \
            float hb2 = (2 * m + 1 < HID) ? readlane_f(h, 32 + 2 * m + 1) : 0.0f; \
            hp##m = pkrtz_(ha, hb2); }
            REP13(HPACK)
#undef HPACK
            float aA0 = xv.x, aA1 = 0.0f, aB0 = xv.y, aB1 = 0.0f;
#define DOTM(m) { if ((m) & 1) { aA1 = dot2acc(wA##m, hp##m, aA1); aB1 = dot2acc(wB##m, hp##m, aB1); } \
                  else         { aA0 = dot2acc(wA##m, hp##m, aA0); aB0 = dot2acc(wB##m, hp##m, aB0); } }
            REP13(DOTM)
#undef DOTM
            const float aA = aA0 + aA1;
            const float aB = aB0 + aB1;
            float e0 = __builtin_exp2f(aA);
            float e1 = __builtin_exp2f(aB);
            float u0 = 1.0f - coef * rcpf_(e0 + 1.0f);   // lower: sig(i); upper: tanh(g)
            float u1 = 1.0f - rcpf_(e1 + 1.0f);          // lower: sig(f); upper: sig(o)
            float si = bcast_row0(u0);
            float sf = bcast_row0(u1);
            cst = sf * cst + si * u0;                    // upper: f*c + i*tanh(g)
            float tc = 1.0f - 2.0f * rcpf_(__builtin_exp2f(LOG2E2 * cst) + 1.0f);
            h = u1 * tc;                                 // upper: sig(o)*tanh(c)
            if (STORE) {
                if (store_lane) *sptr = __float2half(h);
                sptr += sstride;
            }
        }
        pnext += 8 * (G4 / 2);
    }
    if (store_lane) { stH[sidx] = h; stC[sidx] = cst; }
}

// ================= xg GEMM blocks (throughput work, off the critical path) =================
DEV void gemm_l0_block(float* xs, __half* og,
                       const float* __restrict__ x,
                       const float* __restrict__ w_ih, const float* __restrict__ b_ih,
                       const float* __restrict__ b_hh,
                       __half* __restrict__ xgdst, int b, int by, int dir, int seg)
{
    const int tid = threadIdx.x;
    const int t0 = seg * SEG_T + by * TG;
    const float* src = x + ((size_t)b * T_LEN + t0) * HID;
    #pragma unroll
    for (int i = 0; i < 4; ++i) { int idx = tid + 128 * i; if (idx < TG * HID) xs[idx] = src[idx]; }
    __syncthreads();
    if (tid < G4) {
        const int g = tid;
        const float sc = (g >= 2 * HID && g < 3 * HID) ? LOG2E2 : LOG2E;
        float w[HID];
        #pragma unroll
        for (int j = 0; j < HID; ++j) w[j] = w_ih[g * HID + j] * sc;
        const float bias = (b_ih[g] + b_hh[g]) * sc;
        const int pos = (g % HID) * 4 + (g / HID);
        for (int t = 0; t < TG; ++t) {
            const float* xr = xs + t * HID;
            float a0 = bias, a1 = 0.f, a2 = 0.f, a3 = 0.f;
            #pragma unroll
            for (int j = 0; j < 24; j += 4) {
                a0 = fmaf(w[j],     xr[j],     a0);
                a1 = fmaf(w[j + 1], xr[j + 1], a1);
                a2 = fmaf(w[j + 2], xr[j + 2], a2);
                a3 = fmaf(w[j + 3], xr[j + 3], a3);
            }
            a0 = fmaf(w[24], xr[24], a0);
            const int orow = dir ? (TG - 1 - t) : t;    // bwd buffer is time-reversed
            og[orow * G4 + pos] = __float2half((a0 + a1) + (a2 + a3));
        }
    }
    __syncthreads();
    const int rowbase = (dir ? (NTG - 1 - by) : by) * TG;
    unsigned* dst = (unsigned*)xgdst + ((size_t)b * SEG_T + rowbase) * (G4 / 2);
    const unsigned* ogu = (const unsigned*)og;
    #pragma unroll
    for (int i = 0; i < 7; ++i) { int idx = tid + 128 * i; if (idx < TG * (G4 / 2)) dst[idx] = ogu[idx]; }
}

DEV void gemm_l1_block(unsigned* xsu, __half* og,
                       const __half* __restrict__ h0,
                       const float* __restrict__ w_ih, const float* __restrict__ b_ih,
                       const float* __restrict__ b_hh,
                       __half* __restrict__ xgdst, int b, int by, int seg)
{
    const int tid = threadIdx.x;
    const int t0 = seg * SEG_T + by * TG;
    const unsigned* src = (const unsigned*)h0 + ((size_t)b * T_LEN + t0) * HID;
    #pragma unroll
    for (int i = 0; i < 4; ++i) { int idx = tid + 128 * i; if (idx < TG * HID) xsu[idx] = src[idx]; }
    __syncthreads();
    if (tid < G4) {
        const int g = tid;
        const float sc = (g >= 2 * HID && g < 3 * HID) ? LOG2E2 : LOG2E;
        unsigned wp[HID];
        #pragma unroll
        for (int j = 0; j < HID; ++j) {
            __half2 hw = __floats2half2_rn(w_ih[g * (2 * HID) + 2 * j] * sc,
                                           w_ih[g * (2 * HID) + 2 * j + 1] * sc);
            wp[j] = __builtin_bit_cast(unsigned, hw);
        }
        const float bias = (b_ih[g] + b_hh[g]) * sc;
        const int pos = (g % HID) * 4 + (g / HID);
        for (int t = 0; t < TG; ++t) {
            const unsigned* xr = xsu + t * HID;
            float a0 = bias, a1 = 0.f, a2 = 0.f, a3 = 0.f;
            #pragma unroll
            for (int j = 0; j < 24; j += 4) {
                a0 = dot2acc(wp[j],     xr[j],     a0);
                a1 = dot2acc(wp[j + 1], xr[j + 1], a1);
                a2 = dot2acc(wp[j + 2], xr[j + 2], a2);
                a3 = dot2acc(wp[j + 3], xr[j + 3], a3);
            }
            a0 = dot2acc(wp[24], xr[24], a0);
            og[t * G4 + pos] = __float2half((a0 + a1) + (a2 + a3));
        }
    }
    __syncthreads();
    unsigned* dst = (unsigned*)xgdst + ((size_t)b * SEG_T + (size_t)by * TG) * (G4 / 2);
    const unsigned* ogu = (const unsigned*)og;
    #pragma unroll
    for (int i = 0; i < 7; ++i) { int idx = tid + 128 * i; if (idx < TG * (G4 / 2)) dst[idx] = ogu[idx]; }
}

// ================= combined launches: rec(seg s) blocks + gemm(seg s+1) blocks =================
__global__ __launch_bounds__(128, 1) void combo_l0(
    const float* __restrict__ x,
    const float* __restrict__ w_ih_f, const float* __restrict__ b_ih_f, const float* __restrict__ b_hh_f,
    const float* __restrict__ w_ih_b, const float* __restrict__ b_ih_b, const float* __restrict__ b_hh_b,
    const float* __restrict__ w_hh_f, const float* __restrict__ w_hh_b,
    const __half* __restrict__ xg_rd_f, const __half* __restrict__ xg_rd_b,
    __half* __restrict__ xg_wr_f, __half* __restrict__ xg_wr_b,
    __half* __restrict__ h0, float* __restrict__ stH, float* __restrict__ stC,
    int seg_f, int seg_b, int seg_f_next, int seg_b_next, int first)
{
    __shared__ float  xs[TG * HID];
    __shared__ __half og[TG * G4];
    const int bid = blockIdx.x;
    if (bid < 2 * BATCH) {
        if (threadIdx.x >= 64) return;
        const int b = bid & (BATCH - 1);
        const int dir = bid >> 8;
        rec_block<true>(dir ? xg_rd_b : xg_rd_f, dir ? w_hh_b : w_hh_f,
                        h0, stH, stC, b, dir, dir ? seg_b : seg_f, first);
    } else {
        const int g = bid - 2 * BATCH;
        const int b = g & (BATCH - 1);
        const int r = g >> 8;               // 0..2*NTG-1
        const int by = r & (NTG - 1);
        const int dir = r >> 4;             // NTG == 16
        const int seg = dir ? seg_b_next : seg_f_next;
        if (seg < 0) return;
        gemm_l0_block(xs, og, x,
                      dir ? w_ih_b : w_ih_f, dir ? b_ih_b : b_ih_f, dir ? b_hh_b : b_hh_f,
                      dir ? xg_wr_b : xg_wr_f, b, by, dir, seg);
    }
}

__global__ __launch_bounds__(128, 1) void combo_l1(
    const __half* __restrict__ h0,
    const float* __restrict__ w_ih, const float* __restrict__ b_ih, const float* __restrict__ b_hh,
    const float* __restrict__ w_hh,
    const __half* __restrict__ xg_rd, __half* __restrict__ xg_wr,
    float* __restrict__ stH, float* __restrict__ stC,
    int seg, int seg_next, int first)
{
    __shared__ unsigned xsu[TG * HID];
    __shared__ __half   og[TG * G4];
    const int bid = blockIdx.x;
    if (bid < BATCH) {
        if (threadIdx.x >= 64) return;
        rec_block<false>(xg_rd, w_hh, nullptr, stH, stC, bid, 0, seg, first);
    } else {
        const int g = bid - BATCH;
        const int b = g & (BATCH - 1);
        const int by = g >> 8;              // 0..NTG-1
        if (seg_next < 0) return;
        gemm_l1_block(xsu, og, h0, w_ih, b_ih, b_hh, xg_wr, b, by, seg_next);
    }
}

// prologue gemm-only launches
__global__ __launch_bounds__(128) void gemm_l0_pro(
    const float* __restrict__ x,
    const float* __restrict__ w_ih_f, const float* __restrict__ b_ih_f, const float* __restrict__ b_hh_f,
    const float* __restrict__ w_ih_b, const float* __restrict__ b_ih_b, const float* __restrict__ b_hh_b,
    __half* __restrict__ xgf, __half* __restrict__ xgb)
{
    __shared__ float  xs[TG * HID];
    __shared__ __half og[TG * G4];
    const int dir = blockIdx.z;
    gemm_l0_block(xs, og, x,
                  dir ? w_ih_b : w_ih_f, dir ? b_ih_b : b_ih_f, dir ? b_hh_b : b_hh_f,
                  dir ? xgb : xgf, blockIdx.x, blockIdx.y, dir, dir ? (NSEG - 1) : 0);
}

__global__ __launch_bounds__(128) void gemm_l1_pro(
    const __half* __restrict__ h0,
    const float* __restrict__ w_ih, const float* __restrict__ b_ih, const float* __restrict__ b_hh,
    __half* __restrict__ xg)
{
    __shared__ unsigned xsu[TG * HID];
    __shared__ __half   og[TG * G4];
    gemm_l1_block(xsu, og, h0, w_ih, b_ih, b_hh, xg, blockIdx.x, blockIdx.y, 0);
}

// ================= Layer 1 backward (1 step from zero state) + FC head =================
__global__ __launch_bounds__(128) void final_kernel(
    const __half* __restrict__ h0,
    const float* __restrict__ stH1,
    const float* __restrict__ w_ih1b,
    const float* __restrict__ b_ih1b, const float* __restrict__ b_hh1b,
    const float* __restrict__ fc2_w, const float* __restrict__ fc2_b,
    float* __restrict__ out)
{
    const int b   = blockIdx.x;
    const int tid = threadIdx.x;

    __shared__ float inb[2 * HID];
    __shared__ float act[G4];
    __shared__ float hb[HID];

    if (tid < HID) {
        const __half2* rr = (const __half2*)(h0 + ((size_t)b * T_LEN + (T_LEN - 1)) * (2 * HID));
        float2 v = __half22float2(rr[tid]);
        inb[2 * tid] = v.x; inb[2 * tid + 1] = v.y;
    }
    __syncthreads();

    if (tid < G4) {
        float g = b_ih1b[tid] + b_hh1b[tid];
        #pragma unroll
        for (int kk = 0; kk < 2 * HID; ++kk) g += w_ih1b[tid * (2 * HID) + kk] * inb[kk];
        act[tid] = (tid >= 2 * HID && tid < 3 * HID) ? tanhx_(g) : sigm_(g);
    }
    __syncthreads();

    if (tid < HID) {
        float c = act[tid] * act[2 * HID + tid];   // c0 = 0
        hb[tid] = act[3 * HID + tid] * tanhx_(c);
    }
    __syncthreads();

    if (tid == 0) {
        float s = fc2_b[0];
        #pragma unroll
        for (int kk = 0; kk < HID; ++kk) s += fmaxf(stH1[b * 32 + kk], 0.0f) * fc2_w[kk];
        #pragma unroll
        for (int kk = 0; kk < HID; ++kk) s += fmaxf(hb[kk], 0.0f) * fc2_w[HID + kk];
        s = fmaxf(s, 0.0f);
        out[b] = 1.0f / (1.0f + __expf(-s));
    }
}

extern "C" void kernel_launch(void* const* d_in, const int* in_sizes, int n_in,
                              void* d_out, int out_size, void* d_ws, size_t ws_size,
                              hipStream_t stream)
{
    const float* x        = (const float*)d_in[0];
    const float* w_ih_l0f = (const float*)d_in[1];
    const float* w_hh_l0f = (const float*)d_in[2];
    const float* b_ih_l0f = (const float*)d_in[3];
    const float* b_hh_l0f = (const float*)d_in[4];
    const float* w_ih_l0b = (const float*)d_in[5];
    const float* w_hh_l0b = (const float*)d_in[6];
    const float* b_ih_l0b = (const float*)d_in[7];
    const float* b_hh_l0b = (const float*)d_in[8];
    const float* w_ih_l1f = (const float*)d_in[9];
    const float* w_hh_l1f = (const float*)d_in[10];
    const float* b_ih_l1f = (const float*)d_in[11];
    const float* b_hh_l1f = (const float*)d_in[12];
    const float* w_ih_l1b = (const float*)d_in[13];
    const float* b_ih_l1b = (const float*)d_in[15];
    const float* b_hh_l1b = (const float*)d_in[16];
    const float* fc2_w    = (const float*)d_in[17];
    const float* fc2_b    = (const float*)d_in[18];
    float* out = (float*)d_out;

    // ---- workspace layout (~158 MB) ----
    const size_t H0B  = (size_t)BATCH * T_LEN * 2 * HID * sizeof(__half);   // 104,857,600
    const size_t XSEG = (size_t)BATCH * SEG_T * G4 * sizeof(__half);        // 13,107,200
    const size_t PAD  = 4096;
    char* p = (char*)d_ws;
    __half* h0 = (__half*)p;                 p += H0B;
    __half* xgf0 = (__half*)p;               p += XSEG + PAD;
    __half* xgf1 = (__half*)p;               p += XSEG + PAD;
    __half* xgb0 = (__half*)p;               p += XSEG + PAD;
    __half* xgb1 = (__half*)p;               p += XSEG + PAD;
    float* stH0 = (float*)p;                 p += 2 * BATCH * 32 * sizeof(float);
    float* stC0 = (float*)p;                 p += 2 * BATCH * 32 * sizeof(float);
    float* stH1 = (float*)p;                 p += BATCH * 32 * sizeof(float);
    float* stC1 = (float*)p;

    __half* xgf[2] = { xgf0, xgf1 };
    __half* xgb[2] = { xgb0, xgb1 };

    // -------- layer 0 --------
    gemm_l0_pro<<<dim3(BATCH, NTG, 2), 128, 0, stream>>>(
        x, w_ih_l0f, b_ih_l0f, b_hh_l0f, w_ih_l0b, b_ih_l0b, b_hh_l0b, xgf[0], xgb[0]);
    for (int s = 0; s < NSEG; ++s) {
        const int sn = s + 1;
        combo_l0<<<2 * BATCH + BATCH * 2 * NTG, 128, 0, stream>>>(
            x, w_ih_l0f, b_ih_l0f, b_hh_l0f, w_ih_l0b, b_ih_l0b, b_hh_l0b,
            w_hh_l0f, w_hh_l0b,
            xgf[s & 1], xgb[s & 1], xgf[sn & 1], xgb[sn & 1],
            h0, stH0, stC0,
            s, NSEG - 1 - s,
            (sn < NSEG) ? sn : -1, (sn < NSEG) ? (NSEG - 1 - sn) : -1,
            s == 0 ? 1 : 0);
    }
    // -------- layer 1 forward --------
    gemm_l1_pro<<<dim3(BATCH, NTG), 128, 0, stream>>>(
        h0, w_ih_l1f, b_ih_l1f, b_hh_l1f, xgf[0]);
    for (int s = 0; s < NSEG; ++s) {
        const int sn = s + 1;
        combo_l1<<<BATCH + BATCH * NTG, 128, 0, stream>>>(
            h0, w_ih_l1f, b_ih_l1f, b_hh_l1f, w_hh_l1f,
            xgf[s & 1], xgf[sn & 1],
            stH1, stC1,
            s, (sn < NSEG) ? sn : -1, s == 0 ? 1 : 0);
    }
    // -------- layer 1 backward single step + head --------
    final_kernel<<<BATCH, 128, 0, stream>>>(
        h0, stH1, w_ih_l1b, b_ih_l1b, b_hh_l1b, fc2_w, fc2_b, out);
}